// Round 4
// baseline (426.461 us; speedup 1.0000x reference)
//
#include <hip/hip_runtime.h>

#define N_NODES 50000
#define N_EDGES 800000
#define N_GRAPHS 64
#define H 64
#define BN 128                              // nodes per bucket
#define NB ((N_NODES + BN - 1) / BN)        // 391 buckets
#define CHUNK 2048
#define NCHUNK ((N_EDGES + CHUNK - 1) / CHUNK)  // 391

// ws layout (float units). recs first (16B aligned at base).
#define REC_OFF   0                          // float4[N_EDGES] = 12.8 MB
#define ABC_OFF   (4 * N_EDGES)
#define GSUM_OFF  (ABC_OFF + 3 * H)
#define GCNT_OFF  (GSUM_OFF + N_GRAPHS)
#define HIST_OFF  (GCNT_OFF + N_GRAPHS)      // int[NB]
#define OFF_OFF   (HIST_OFF + NB)            // int[NB+1]
#define CUR_OFF   (OFF_OFF + NB + 1)         // int[NB]

// ---------------------------------------------------------------------------
// k_prep: fold A/B/C, zero bucket hist + graph accumulators.
__global__ __launch_bounds__(256) void k_prep(
    float* __restrict__ abc, float* __restrict__ gsum, float* __restrict__ gcnt,
    int* __restrict__ hist,
    const float* __restrict__ Wn, const float* __restrict__ bn,
    const float* __restrict__ We, const float* __restrict__ be,
    const float* __restrict__ Wm, const float* __restrict__ bm)
{
    const int t = threadIdx.x;
    for (int i = t; i < NB; i += 256) hist[i] = 0;
    if (t < N_GRAPHS) { gsum[t] = 0.f; gcnt[t] = 0.f; }
    if (t < H) {
        const int k = t;
        float a = 0.f, b = 0.f, c = 0.f;
        #pragma unroll
        for (int i = 0; i < H; ++i) {
            float wt = Wm[i * H + k];
            float wb = Wm[(H + i) * H + k];
            a = fmaf(Wn[i], wt, a);
            b = fmaf(We[i], wb, b);
            c = fmaf(bn[i], wt, c);
            c = fmaf(be[i], wb, c);
        }
        abc[k]         = a;
        abc[H + k]     = b;
        abc[2 * H + k] = c + bm[k];
    }
}

// ---------------------------------------------------------------------------
// k_hist: LDS-privatized bucket histogram of dst>>7.
__global__ __launch_bounds__(256) void k_hist(
    const int* __restrict__ ei, int* __restrict__ hist)
{
    __shared__ int lh[NB];
    const int t = threadIdx.x;
    for (int b = t; b < NB; b += 256) lh[b] = 0;
    __syncthreads();
    const int* __restrict__ dst = ei + N_EDGES;
    const int tid = blockIdx.x * blockDim.x + threadIdx.x;
    const int nthreads = gridDim.x * blockDim.x;
    for (int e = tid; e < N_EDGES; e += nthreads)
        atomicAdd(&lh[dst[e] >> 7], 1);
    __syncthreads();
    for (int b = t; b < NB; b += 256) {
        const int v = lh[b];
        if (v) atomicAdd(&hist[b], v);
    }
}

// ---------------------------------------------------------------------------
// k_scan: single-WG 512-wide Hillis-Steele scan of hist -> off (NB+1), cur.
__global__ __launch_bounds__(512) void k_scan(
    const int* __restrict__ hist, int* __restrict__ off, int* __restrict__ cur)
{
    __shared__ int s[512];
    const int t = threadIdx.x;
    const int v = (t < NB) ? hist[t] : 0;
    s[t] = v;
    __syncthreads();
    #pragma unroll
    for (int d = 1; d < 512; d <<= 1) {
        const int add = (t >= d) ? s[t - d] : 0;
        __syncthreads();
        s[t] += add;
        __syncthreads();
    }
    if (t == 0) off[0] = 0;
    if (t < NB) {
        off[t + 1] = s[t];        // inclusive
        cur[t]     = s[t] - v;    // exclusive
    }
}

// ---------------------------------------------------------------------------
// k_bin: staged scatter. Each WG owns a 2048-edge chunk; reserves one
// contiguous run per bucket so all writes to a line come from one WG/XCD.
__global__ __launch_bounds__(256) void k_bin(
    const float* __restrict__ x, const float* __restrict__ ea,
    const int* __restrict__ ei, int* __restrict__ cur,
    float4* __restrict__ recs)
{
    __shared__ int lh[NB], lbase[NB], lcur[NB];
    const int t = threadIdx.x;
    for (int b = t; b < NB; b += 256) { lh[b] = 0; lcur[b] = 0; }
    __syncthreads();

    const int e0 = blockIdx.x * CHUNK;
    const int* __restrict__ src = ei;
    const int* __restrict__ dst = ei + N_EDGES;

    for (int i = t; i < CHUNK; i += 256) {
        const int e = e0 + i;
        if (e < N_EDGES) atomicAdd(&lh[dst[e] >> 7], 1);
    }
    __syncthreads();
    for (int b = t; b < NB; b += 256) {
        const int v = lh[b];
        if (v) lbase[b] = atomicAdd(&cur[b], v);
    }
    __syncthreads();
    for (int i = t; i < CHUNK; i += 256) {
        const int e = e0 + i;
        if (e < N_EDGES) {
            const int d = dst[e];
            const int b = d >> 7;
            const int lp = atomicAdd(&lcur[b], 1);
            recs[lbase[b] + lp] =
                make_float4(x[src[e]], ea[e], __int_as_float(d & (BN - 1)), 0.f);
        }
    }
}

// ---------------------------------------------------------------------------
// k_fused: per bucket — aggregate records into LDS, then matvec + ReLU +
// output-dot + graph pooling. No global aggr array.
__global__ __launch_bounds__(256) void k_fused(
    const float4* __restrict__ recs, const int* __restrict__ off,
    const float* __restrict__ abc, const float* __restrict__ Wu,
    const float* __restrict__ bu, const float* __restrict__ Wo,
    const int* __restrict__ batch,
    float* __restrict__ gsum, float* __restrict__ gcnt)
{
    __shared__ float sAg[BN * 65];        // 33.3 KB, row stride 65 (bank-safe)
    __shared__ float sWuT[64 * 68];       // WuT[k][i], stride 68 (16B aligned)
    __shared__ float sBu[64], sWo[64];
    __shared__ float lsum[N_GRAPHS], lcnt[N_GRAPHS];

    const int t = threadIdx.x;
    for (int i = t; i < BN * 65; i += 256) sAg[i] = 0.f;
    for (int i = t; i < H * H; i += 256) {
        const int ii = i >> 6, k = i & 63;
        sWuT[k * 68 + ii] = Wu[i];
    }
    if (t < 64) { sBu[t] = bu[t]; sWo[t] = Wo[t]; }
    if (t < N_GRAPHS) { lsum[t] = 0.f; lcnt[t] = 0.f; }

    const int lane = t & 63;
    const int w    = t >> 6;
    const float A = abc[lane];
    const float B = abc[H + lane];
    const float C = abc[2 * H + lane];
    __syncthreads();

    // aggregate: one record per wave-iteration (broadcast load)
    const int b  = blockIdx.x;
    const int st = off[b];
    const int en = off[b + 1];
    for (int idx = st + w; idx < en; idx += 4) {
        const float4 r = recs[idx];
        const int d = __float_as_int(r.z);
        const float m = fmaxf(fmaf(r.x, A, fmaf(r.y, B, C)), 0.f);
        atomicAdd(&sAg[d * 65 + lane], m);
    }
    __syncthreads();

    // matvec: 2 threads per node, split over k-halves
    const int n    = t >> 1;
    const int kh   = t & 1;
    const int node = b * BN + n;
    float s = 0.f;
    if (node < N_NODES) {
        float a[64];
        #pragma unroll
        for (int i = 0; i < 64; ++i) a[i] = sAg[n * 65 + i];
        for (int kc = 0; kc < 32; ++kc) {
            const int k = kh * 32 + kc;
            const float4* __restrict__ wr = (const float4*)&sWuT[k * 68];
            float t0 = 0.f, t1 = 0.f, t2 = 0.f, t3 = 0.f;
            #pragma unroll
            for (int ii = 0; ii < 16; ii += 4) {
                float4 ww;
                ww = wr[ii + 0]; t0 = fmaf(a[4*ii+0],  ww.x, t0); t0 = fmaf(a[4*ii+1],  ww.y, t0);
                                 t0 = fmaf(a[4*ii+2],  ww.z, t0); t0 = fmaf(a[4*ii+3],  ww.w, t0);
                ww = wr[ii + 1]; t1 = fmaf(a[4*ii+4],  ww.x, t1); t1 = fmaf(a[4*ii+5],  ww.y, t1);
                                 t1 = fmaf(a[4*ii+6],  ww.z, t1); t1 = fmaf(a[4*ii+7],  ww.w, t1);
                ww = wr[ii + 2]; t2 = fmaf(a[4*ii+8],  ww.x, t2); t2 = fmaf(a[4*ii+9],  ww.y, t2);
                                 t2 = fmaf(a[4*ii+10], ww.z, t2); t2 = fmaf(a[4*ii+11], ww.w, t2);
                ww = wr[ii + 3]; t3 = fmaf(a[4*ii+12], ww.x, t3); t3 = fmaf(a[4*ii+13], ww.y, t3);
                                 t3 = fmaf(a[4*ii+14], ww.z, t3); t3 = fmaf(a[4*ii+15], ww.w, t3);
            }
            const float tt = (t0 + t1) + (t2 + t3);
            s = fmaf(fmaxf(tt + sBu[k], 0.f), sWo[k], s);
        }
    }
    s += __shfl_xor(s, 1);
    if (node < N_NODES && kh == 0) {
        const int g = batch[node];
        atomicAdd(&lsum[g], s);
        atomicAdd(&lcnt[g], 1.f);
    }
    __syncthreads();
    if (t < N_GRAPHS && lcnt[t] != 0.f) {
        atomicAdd(&gsum[t], lsum[t]);
        atomicAdd(&gcnt[t], lcnt[t]);
    }
}

// ---------------------------------------------------------------------------
__global__ void k_final(const float* __restrict__ gsum,
                        const float* __restrict__ gcnt,
                        const float* __restrict__ bo,
                        float* __restrict__ out)
{
    const int g = threadIdx.x;
    if (g < N_GRAPHS)
        out[g] = gsum[g] / fmaxf(gcnt[g], 1.f) + bo[0];
}

// ---------------------------------------------------------------------------
extern "C" void kernel_launch(void* const* d_in, const int* in_sizes, int n_in,
                              void* d_out, int out_size, void* d_ws, size_t ws_size,
                              hipStream_t stream)
{
    const float* x      = (const float*)d_in[0];
    const float* ea     = (const float*)d_in[1];
    const int*   ei     = (const int*)  d_in[2];
    const int*   batch  = (const int*)  d_in[3];
    const float* Wn     = (const float*)d_in[4];
    const float* bn     = (const float*)d_in[5];
    const float* We     = (const float*)d_in[6];
    const float* be     = (const float*)d_in[7];
    const float* Wm     = (const float*)d_in[8];
    const float* bm     = (const float*)d_in[9];
    const float* Wu     = (const float*)d_in[10];
    const float* bu     = (const float*)d_in[11];
    const float* Wo     = (const float*)d_in[12];
    const float* bo     = (const float*)d_in[13];

    float*  ws   = (float*)d_ws;
    float4* recs = (float4*)(ws + REC_OFF);
    float*  abc  = ws + ABC_OFF;
    float*  gsum = ws + GSUM_OFF;
    float*  gcnt = ws + GCNT_OFF;
    int*    hist = (int*)(ws + HIST_OFF);
    int*    off  = (int*)(ws + OFF_OFF);
    int*    cur  = (int*)(ws + CUR_OFF);
    float*  out  = (float*)d_out;

    k_prep<<<1, 256, 0, stream>>>(abc, gsum, gcnt, hist, Wn, bn, We, be, Wm, bm);
    k_hist<<<391, 256, 0, stream>>>(ei, hist);
    k_scan<<<1, 512, 0, stream>>>(hist, off, cur);
    k_bin<<<NCHUNK, 256, 0, stream>>>(x, ea, ei, cur, recs);
    k_fused<<<NB, 256, 0, stream>>>(recs, off, abc, Wu, bu, Wo, batch, gsum, gcnt);
    k_final<<<1, 64, 0, stream>>>(gsum, gcnt, bo, out);
}

// Round 5
// 142.990 us; speedup vs baseline: 2.9824x; 2.9824x over previous
//
#include <hip/hip_runtime.h>

#define N_NODES 50000
#define N_EDGES 800000
#define N_GRAPHS 64
#define H 64
#define BN 128                                   // nodes per bucket
#define NB ((N_NODES + BN - 1) / BN)             // 391
#define CHUNK 2048
#define NCHUNK ((N_EDGES + CHUNK - 1) / CHUNK)   // 391

// ws layout (float units). aggr ALIASES recs (recs dead after k_fsort).
#define REC_OFF   0                              // float4[N_EDGES] = 12.8 MB
#define AGGR_OFF  0                              // float[N_NODES*H] = 12.8 MB
#define PAIRS_OFF (4 * N_EDGES)                  // float2[N_EDGES] = 6.4 MB
#define NOFF_OFF  (PAIRS_OFF + 2 * N_EDGES)      // int[N_NODES]
#define NCNT_OFF  (NOFF_OFF + N_NODES)           // int[N_NODES]
#define WUT_OFF   (NCNT_OFF + N_NODES)           // float[H*H]
#define ABC_OFF   (WUT_OFF + H * H)              // float[3*H]
#define GSUM_OFF  (ABC_OFF + 3 * H)
#define GCNT_OFF  (GSUM_OFF + N_GRAPHS)
#define HIST_OFF  (GCNT_OFF + N_GRAPHS)          // int[NB]
#define BOFF_OFF  (HIST_OFF + NB)                // int[NB+1]
#define BCUR_OFF  (BOFF_OFF + NB + 1)            // int[NB]

// ---------------------------------------------------------------------------
// k_prep: zero hist/gsum/gcnt, fold A/B/C, transpose W_upd.
__global__ __launch_bounds__(256) void k_prep(
    int* __restrict__ hist,
    float* __restrict__ abc, float* __restrict__ wut,
    float* __restrict__ gsum, float* __restrict__ gcnt,
    const float* __restrict__ Wn, const float* __restrict__ bn,
    const float* __restrict__ We, const float* __restrict__ be,
    const float* __restrict__ Wm, const float* __restrict__ bm,
    const float* __restrict__ Wu)
{
    const int t = threadIdx.x;
    for (int i = t; i < NB; i += 256) hist[i] = 0;
    if (t < N_GRAPHS) { gsum[t] = 0.f; gcnt[t] = 0.f; }
    for (int idx = t; idx < H * H; idx += 256) {
        const int i = idx >> 6, k = idx & 63;
        wut[k * H + i] = Wu[i * H + k];
    }
    if (t < H) {
        const int k = t;
        float a = 0.f, b = 0.f, c = 0.f;
        #pragma unroll
        for (int i = 0; i < H; ++i) {
            float wt = Wm[i * H + k];
            float wb = Wm[(H + i) * H + k];
            a = fmaf(Wn[i], wt, a);
            b = fmaf(We[i], wb, b);
            c = fmaf(bn[i], wt, c);
            c = fmaf(be[i], wb, c);
        }
        abc[k]         = a;
        abc[H + k]     = b;
        abc[2 * H + k] = c + bm[k];
    }
}

// ---------------------------------------------------------------------------
// k_hist: LDS-privatized coarse-bucket histogram of dst>>7.
__global__ __launch_bounds__(256) void k_hist(
    const int* __restrict__ ei, int* __restrict__ hist)
{
    __shared__ int lh[NB];
    const int t = threadIdx.x;
    for (int b = t; b < NB; b += 256) lh[b] = 0;
    __syncthreads();
    const int* __restrict__ dst = ei + N_EDGES;
    const int tid = blockIdx.x * blockDim.x + threadIdx.x;
    const int nthreads = gridDim.x * blockDim.x;
    for (int e = tid; e < N_EDGES; e += nthreads)
        atomicAdd(&lh[dst[e] >> 7], 1);
    __syncthreads();
    for (int b = t; b < NB; b += 256) {
        const int v = lh[b];
        if (v) atomicAdd(&hist[b], v);
    }
}

// ---------------------------------------------------------------------------
// k_scan: single-WG scan of NB buckets -> boff[NB+1], bcur (exclusive).
__global__ __launch_bounds__(512) void k_scan(
    const int* __restrict__ hist, int* __restrict__ boff, int* __restrict__ bcur)
{
    __shared__ int s[512];
    const int t = threadIdx.x;
    const int v = (t < NB) ? hist[t] : 0;
    s[t] = v;
    __syncthreads();
    #pragma unroll
    for (int d = 1; d < 512; d <<= 1) {
        const int add = (t >= d) ? s[t - d] : 0;
        __syncthreads();
        s[t] += add;
        __syncthreads();
    }
    if (t == 0) boff[0] = 0;
    if (t < NB) {
        boff[t + 1] = s[t];
        bcur[t]     = s[t] - v;
    }
}

// ---------------------------------------------------------------------------
// k_bin: staged coarse scatter. Each WG reserves one contiguous run per
// bucket -> all writes to a line come from one WG/XCD -> L2 merges.
__global__ __launch_bounds__(256) void k_bin(
    const float* __restrict__ x, const float* __restrict__ ea,
    const int* __restrict__ ei, int* __restrict__ bcur,
    float4* __restrict__ recs)
{
    __shared__ int lh[NB], lbase[NB], lcur[NB];
    const int t = threadIdx.x;
    for (int b = t; b < NB; b += 256) { lh[b] = 0; lcur[b] = 0; }
    __syncthreads();

    const int e0 = blockIdx.x * CHUNK;
    const int* __restrict__ src = ei;
    const int* __restrict__ dst = ei + N_EDGES;

    for (int i = t; i < CHUNK; i += 256) {
        const int e = e0 + i;
        if (e < N_EDGES) atomicAdd(&lh[dst[e] >> 7], 1);
    }
    __syncthreads();
    for (int b = t; b < NB; b += 256) {
        const int v = lh[b];
        if (v) lbase[b] = atomicAdd(&bcur[b], v);
    }
    __syncthreads();
    for (int i = t; i < CHUNK; i += 256) {
        const int e = e0 + i;
        if (e < N_EDGES) {
            const int d = dst[e];
            const int b = d >> 7;
            const int lp = atomicAdd(&lcur[b], 1);
            recs[lbase[b] + lp] =
                make_float4(x[src[e]], ea[e], __int_as_float(d & (BN - 1)), 0.f);
        }
    }
}

// ---------------------------------------------------------------------------
// k_fsort: one WG per bucket. LDS 128-bin hist + scan; rewrite records to
// exact node-sorted order (contiguous ~16KB write window per WG). Emits
// per-node noff/ncnt.
__global__ __launch_bounds__(256) void k_fsort(
    const float4* __restrict__ recs, const int* __restrict__ boff,
    float2* __restrict__ pairs,
    int* __restrict__ noff, int* __restrict__ ncnt)
{
    __shared__ int lh[BN], le[BN], lc[BN];
    const int t = threadIdx.x;
    const int b = blockIdx.x;
    if (t < BN) lh[t] = 0;
    __syncthreads();

    const int st = boff[b];
    const int m  = boff[b + 1] - st;

    for (int i = t; i < m; i += 256)
        atomicAdd(&lh[__float_as_int(recs[st + i].z)], 1);
    __syncthreads();

    if (t < BN) le[t] = lh[t];
    __syncthreads();
    #pragma unroll
    for (int d = 1; d < BN; d <<= 1) {
        const int add = (t >= d && t < BN) ? le[t - d] : 0;
        __syncthreads();
        if (t < BN) le[t] += add;
        __syncthreads();
    }
    if (t < BN) {
        const int excl = le[t] - lh[t];
        lc[t] = excl;
        const int node = b * BN + t;
        if (node < N_NODES) {
            noff[node] = st + excl;
            ncnt[node] = lh[t];
        }
    }
    __syncthreads();

    for (int i = t; i < m; i += 256) {
        const float4 r = recs[st + i];
        const int d = __float_as_int(r.z);
        const int rk = atomicAdd(&lc[d], 1);
        pairs[st + rk] = make_float2(r.x, r.y);
    }
}

// ---------------------------------------------------------------------------
// k_aggr: one wave per node; lane k = hidden component k. No atomics.
__global__ __launch_bounds__(256) void k_aggr(
    const float2* __restrict__ pairs, const int* __restrict__ noff,
    const int* __restrict__ ncnt, const float* __restrict__ abc,
    float* __restrict__ aggr)
{
    const int lane = threadIdx.x & 63;
    const int w = (blockIdx.x * blockDim.x + threadIdx.x) >> 6;
    if (w >= N_NODES) return;

    const float A = abc[lane];
    const float B = abc[H + lane];
    const float C = abc[2 * H + lane];

    const int st = noff[w];
    const int c  = ncnt[w];
    float s = 0.f;
    for (int j = 0; j < c; ++j) {
        const float2 p = pairs[st + j];
        s += fmaxf(fmaf(p.x, A, fmaf(p.y, B, C)), 0.f);
    }
    aggr[w * H + lane] = s;
}

// ---------------------------------------------------------------------------
// k_node: lane-per-node matvec + relu + dot, LDS-atomic graph reduce.
__global__ __launch_bounds__(256) void k_node(
    const float* __restrict__ aggr, const int* __restrict__ batch,
    const float* __restrict__ wut, const float* __restrict__ bu,
    const float* __restrict__ Wo,
    float* __restrict__ gsum, float* __restrict__ gcnt)
{
    __shared__ float lsum[N_GRAPHS];
    __shared__ float lcnt[N_GRAPHS];
    if (threadIdx.x < N_GRAPHS) { lsum[threadIdx.x] = 0.f; lcnt[threadIdx.x] = 0.f; }
    __syncthreads();

    const int n = blockIdx.x * blockDim.x + threadIdx.x;
    if (n < N_NODES) {
        float4 a4[16];
        const float4* __restrict__ ap = (const float4*)(aggr + n * H);
        #pragma unroll
        for (int i = 0; i < 16; ++i) a4[i] = ap[i];

        float s = 0.f;
        for (int k = 0; k < H; ++k) {
            const float4* __restrict__ w4 = (const float4*)(wut + k * H);
            float t0 = 0.f, t1 = 0.f, t2 = 0.f, t3 = 0.f;
            #pragma unroll
            for (int i = 0; i < 16; i += 4) {
                float4 w;
                w = w4[i + 0]; t0 = fmaf(a4[i+0].x, w.x, t0); t0 = fmaf(a4[i+0].y, w.y, t0);
                               t0 = fmaf(a4[i+0].z, w.z, t0); t0 = fmaf(a4[i+0].w, w.w, t0);
                w = w4[i + 1]; t1 = fmaf(a4[i+1].x, w.x, t1); t1 = fmaf(a4[i+1].y, w.y, t1);
                               t1 = fmaf(a4[i+1].z, w.z, t1); t1 = fmaf(a4[i+1].w, w.w, t1);
                w = w4[i + 2]; t2 = fmaf(a4[i+2].x, w.x, t2); t2 = fmaf(a4[i+2].y, w.y, t2);
                               t2 = fmaf(a4[i+2].z, w.z, t2); t2 = fmaf(a4[i+2].w, w.w, t2);
                w = w4[i + 3]; t3 = fmaf(a4[i+3].x, w.x, t3); t3 = fmaf(a4[i+3].y, w.y, t3);
                               t3 = fmaf(a4[i+3].z, w.z, t3); t3 = fmaf(a4[i+3].w, w.w, t3);
            }
            const float t = (t0 + t1) + (t2 + t3);
            s = fmaf(fmaxf(t + bu[k], 0.f), Wo[k], s);
        }
        const int g = batch[n];
        atomicAdd(&lsum[g], s);
        atomicAdd(&lcnt[g], 1.f);
    }
    __syncthreads();
    if (threadIdx.x < N_GRAPHS) {
        const float ls = lsum[threadIdx.x];
        const float lc = lcnt[threadIdx.x];
        if (lc != 0.f) {
            atomicAdd(&gsum[threadIdx.x], ls);
            atomicAdd(&gcnt[threadIdx.x], lc);
        }
    }
}

// ---------------------------------------------------------------------------
__global__ void k_final(const float* __restrict__ gsum,
                        const float* __restrict__ gcnt,
                        const float* __restrict__ bo,
                        float* __restrict__ out)
{
    const int g = threadIdx.x;
    if (g < N_GRAPHS)
        out[g] = gsum[g] / fmaxf(gcnt[g], 1.f) + bo[0];
}

// ---------------------------------------------------------------------------
extern "C" void kernel_launch(void* const* d_in, const int* in_sizes, int n_in,
                              void* d_out, int out_size, void* d_ws, size_t ws_size,
                              hipStream_t stream)
{
    const float* x      = (const float*)d_in[0];
    const float* ea     = (const float*)d_in[1];
    const int*   ei     = (const int*)  d_in[2];
    const int*   batch  = (const int*)  d_in[3];
    const float* Wn     = (const float*)d_in[4];
    const float* bn     = (const float*)d_in[5];
    const float* We     = (const float*)d_in[6];
    const float* be     = (const float*)d_in[7];
    const float* Wm     = (const float*)d_in[8];
    const float* bm     = (const float*)d_in[9];
    const float* Wu     = (const float*)d_in[10];
    const float* bu     = (const float*)d_in[11];
    const float* Wo     = (const float*)d_in[12];
    const float* bo     = (const float*)d_in[13];

    float*  ws    = (float*)d_ws;
    float4* recs  = (float4*)(ws + REC_OFF);
    float*  aggr  = ws + AGGR_OFF;             // aliases recs (stream-ordered)
    float2* pairs = (float2*)(ws + PAIRS_OFF);
    int*    noff  = (int*)(ws + NOFF_OFF);
    int*    ncnt  = (int*)(ws + NCNT_OFF);
    float*  wut   = ws + WUT_OFF;
    float*  abc   = ws + ABC_OFF;
    float*  gsum  = ws + GSUM_OFF;
    float*  gcnt  = ws + GCNT_OFF;
    int*    hist  = (int*)(ws + HIST_OFF);
    int*    boff  = (int*)(ws + BOFF_OFF);
    int*    bcur  = (int*)(ws + BCUR_OFF);
    float*  out   = (float*)d_out;

    k_prep<<<1, 256, 0, stream>>>(hist, abc, wut, gsum, gcnt,
                                  Wn, bn, We, be, Wm, bm, Wu);
    k_hist<<<NB, 256, 0, stream>>>(ei, hist);
    k_scan<<<1, 512, 0, stream>>>(hist, boff, bcur);
    k_bin<<<NCHUNK, 256, 0, stream>>>(x, ea, ei, bcur, recs);
    k_fsort<<<NB, 256, 0, stream>>>(recs, boff, pairs, noff, ncnt);
    k_aggr<<<(N_NODES * 64 + 255) / 256, 256, 0, stream>>>(pairs, noff, ncnt, abc, aggr);
    k_node<<<(N_NODES + 255) / 256, 256, 0, stream>>>(aggr, batch, wut, bu, Wo,
                                                      gsum, gcnt);
    k_final<<<1, 64, 0, stream>>>(gsum, gcnt, bo, out);
}

// Round 6
// 105.320 us; speedup vs baseline: 4.0492x; 1.3577x over previous
//
#include <hip/hip_runtime.h>

#define N_NODES 50000
#define N_EDGES 800000
#define N_GRAPHS 64
#define H 64
#define BN 128                                   // nodes per bucket
#define NB ((N_NODES + BN - 1) / BN)             // 391
#define CHUNK 2048
#define NCHUNK ((N_EDGES + CHUNK - 1) / CHUNK)   // 391
#define STAGE 2560                               // k_fsort LDS stage (float2)

#define AGG_BLOCKS 2048
#define AGG_WAVES (AGG_BLOCKS * 4)               // 8192
#define AGG_ROUNDS ((N_NODES + AGG_WAVES - 1) / AGG_WAVES)  // 7

// ws layout (float units)
#define REC_OFF   0                              // float4[N_EDGES] = 12.8 MB
#define PAIRS_OFF (4 * N_EDGES)                  // float2[N_EDGES] = 6.4 MB
#define SARR_OFF  (PAIRS_OFF + 2 * N_EDGES)      // float[N_NODES]
#define NOFF_OFF  (SARR_OFF + N_NODES)           // int[N_NODES]
#define NCNT_OFF  (NOFF_OFF + N_NODES)           // int[N_NODES]
#define ABC_OFF   (NCNT_OFF + N_NODES)           // float[3*H]
#define GSUM_OFF  (ABC_OFF + 3 * H)
#define GCNT_OFF  (GSUM_OFF + N_GRAPHS)
#define HIST_OFF  (GCNT_OFF + N_GRAPHS)          // int[NB]
#define BOFF_OFF  (HIST_OFF + NB)                // int[NB+1]
#define BCUR_OFF  (BOFF_OFF + NB + 1)            // int[NB]

// ---------------------------------------------------------------------------
__global__ __launch_bounds__(256) void k_prep(
    int* __restrict__ hist, float* __restrict__ abc,
    float* __restrict__ gsum, float* __restrict__ gcnt,
    const float* __restrict__ Wn, const float* __restrict__ bn,
    const float* __restrict__ We, const float* __restrict__ be,
    const float* __restrict__ Wm, const float* __restrict__ bm)
{
    const int t = threadIdx.x;
    for (int i = t; i < NB; i += 256) hist[i] = 0;
    if (t < N_GRAPHS) { gsum[t] = 0.f; gcnt[t] = 0.f; }
    if (t < H) {
        const int k = t;
        float a = 0.f, b = 0.f, c = 0.f;
        #pragma unroll
        for (int i = 0; i < H; ++i) {
            float wt = Wm[i * H + k];
            float wb = Wm[(H + i) * H + k];
            a = fmaf(Wn[i], wt, a);
            b = fmaf(We[i], wb, b);
            c = fmaf(bn[i], wt, c);
            c = fmaf(be[i], wb, c);
        }
        abc[k]         = a;
        abc[H + k]     = b;
        abc[2 * H + k] = c + bm[k];
    }
}

// ---------------------------------------------------------------------------
__global__ __launch_bounds__(256) void k_hist(
    const int* __restrict__ ei, int* __restrict__ hist)
{
    __shared__ int lh[NB];
    const int t = threadIdx.x;
    for (int b = t; b < NB; b += 256) lh[b] = 0;
    __syncthreads();
    const int* __restrict__ dst = ei + N_EDGES;
    const int tid = blockIdx.x * blockDim.x + threadIdx.x;
    const int nthreads = gridDim.x * blockDim.x;
    for (int e = tid; e < N_EDGES; e += nthreads)
        atomicAdd(&lh[dst[e] >> 7], 1);
    __syncthreads();
    for (int b = t; b < NB; b += 256) {
        const int v = lh[b];
        if (v) atomicAdd(&hist[b], v);
    }
}

// ---------------------------------------------------------------------------
__global__ __launch_bounds__(512) void k_scan(
    const int* __restrict__ hist, int* __restrict__ boff, int* __restrict__ bcur)
{
    __shared__ int s[512];
    const int t = threadIdx.x;
    const int v = (t < NB) ? hist[t] : 0;
    s[t] = v;
    __syncthreads();
    #pragma unroll
    for (int d = 1; d < 512; d <<= 1) {
        const int add = (t >= d) ? s[t - d] : 0;
        __syncthreads();
        s[t] += add;
        __syncthreads();
    }
    if (t == 0) boff[0] = 0;
    if (t < NB) {
        boff[t + 1] = s[t];
        bcur[t]     = s[t] - v;
    }
}

// ---------------------------------------------------------------------------
// k_bin: staged coarse scatter (one contiguous run per WG per bucket).
__global__ __launch_bounds__(256) void k_bin(
    const float* __restrict__ x, const float* __restrict__ ea,
    const int* __restrict__ ei, int* __restrict__ bcur,
    float4* __restrict__ recs)
{
    __shared__ int lh[NB], lbase[NB], lcur[NB];
    const int t = threadIdx.x;
    for (int b = t; b < NB; b += 256) { lh[b] = 0; lcur[b] = 0; }
    __syncthreads();

    const int e0 = blockIdx.x * CHUNK;
    const int* __restrict__ src = ei;
    const int* __restrict__ dst = ei + N_EDGES;

    for (int i = t; i < CHUNK; i += 256) {
        const int e = e0 + i;
        if (e < N_EDGES) atomicAdd(&lh[dst[e] >> 7], 1);
    }
    __syncthreads();
    for (int b = t; b < NB; b += 256) {
        const int v = lh[b];
        if (v) lbase[b] = atomicAdd(&bcur[b], v);
    }
    __syncthreads();
    for (int i = t; i < CHUNK; i += 256) {
        const int e = e0 + i;
        if (e < N_EDGES) {
            const int d = dst[e];
            const int b = d >> 7;
            const int lp = atomicAdd(&lcur[b], 1);
            recs[lbase[b] + lp] =
                make_float4(x[src[e]], ea[e], __int_as_float(d & (BN - 1)), 0.f);
        }
    }
}

// ---------------------------------------------------------------------------
// k_fsort: per-bucket node sort; pairs staged in LDS then flushed coalesced.
__global__ __launch_bounds__(256) void k_fsort(
    const float4* __restrict__ recs, const int* __restrict__ boff,
    float2* __restrict__ pairs,
    int* __restrict__ noff, int* __restrict__ ncnt)
{
    __shared__ int lh[BN], le[BN], lc[BN];
    __shared__ float2 st2[STAGE];
    const int t = threadIdx.x;
    const int b = blockIdx.x;
    if (t < BN) lh[t] = 0;
    __syncthreads();

    const int st = boff[b];
    const int m  = boff[b + 1] - st;

    for (int i = t; i < m; i += 256)
        atomicAdd(&lh[__float_as_int(recs[st + i].z)], 1);
    __syncthreads();

    if (t < BN) le[t] = lh[t];
    __syncthreads();
    #pragma unroll
    for (int d = 1; d < BN; d <<= 1) {
        const int add = (t >= d && t < BN) ? le[t - d] : 0;
        __syncthreads();
        if (t < BN) le[t] += add;
        __syncthreads();
    }
    if (t < BN) {
        const int excl = le[t] - lh[t];
        lc[t] = excl;
        const int node = b * BN + t;
        if (node < N_NODES) {
            noff[node] = st + excl;
            ncnt[node] = lh[t];
        }
    }
    __syncthreads();

    if (m <= STAGE) {
        for (int i = t; i < m; i += 256) {
            const float4 r = recs[st + i];
            const int rk = atomicAdd(&lc[__float_as_int(r.z)], 1);
            st2[rk] = make_float2(r.x, r.y);
        }
        __syncthreads();
        for (int i = t; i < m; i += 256)
            pairs[st + i] = st2[i];
    } else {
        for (int i = t; i < m; i += 256) {
            const float4 r = recs[st + i];
            const int rk = atomicAdd(&lc[__float_as_int(r.z)], 1);
            pairs[st + rk] = make_float2(r.x, r.y);
        }
    }
}

// ---------------------------------------------------------------------------
// k_aggmv: one wave per node (grid-strided, uniform rounds).
// Phase A: lane k aggregates component k over the node's edges.
// Phase B: row -> LDS, barrier, 64x64 matvec (Wu staged in LDS), ReLU-dot,
//          wave-reduce, write per-node scalar.
__global__ __launch_bounds__(256) void k_aggmv(
    const float2* __restrict__ pairs, const int* __restrict__ noff,
    const int* __restrict__ ncnt, const float* __restrict__ abc,
    const float* __restrict__ Wu, const float* __restrict__ bu,
    const float* __restrict__ Wo, float* __restrict__ sarr)
{
    __shared__ float sWu[H * H];     // 16 KB, layout [i][k] (as Wu)
    __shared__ float sA[4][H];       // per-wave aggregate row

    const int t = threadIdx.x;
    for (int i = t; i < H * H; i += 256) sWu[i] = Wu[i];

    const int lane = t & 63;
    const int w    = t >> 6;
    const float A   = abc[lane];
    const float B   = abc[H + lane];
    const float C   = abc[2 * H + lane];
    const float bul = bu[lane];
    const float wol = Wo[lane];
    __syncthreads();

    const int gw = blockIdx.x * 4 + w;

    #pragma unroll 1
    for (int r = 0; r < AGG_ROUNDS; ++r) {
        const int n = r * AGG_WAVES + gw;
        if (n < N_NODES) {
            const int st = noff[n];
            const int c  = ncnt[n];
            float s = 0.f;
            for (int j = 0; j < c; ++j) {
                const float2 p = pairs[st + j];
                s += fmaxf(fmaf(p.x, A, fmaf(p.y, B, C)), 0.f);
            }
            sA[w][lane] = s;
        }
        __syncthreads();
        if (n < N_NODES) {
            const float* __restrict__ a = sA[w];
            float t0 = 0.f, t1 = 0.f, t2 = 0.f, t3 = 0.f;
            #pragma unroll
            for (int i = 0; i < H; i += 4) {
                const float4 av = *(const float4*)&a[i];   // uniform broadcast
                t0 = fmaf(av.x, sWu[(i + 0) * H + lane], t0);
                t1 = fmaf(av.y, sWu[(i + 1) * H + lane], t1);
                t2 = fmaf(av.z, sWu[(i + 2) * H + lane], t2);
                t3 = fmaf(av.w, sWu[(i + 3) * H + lane], t3);
            }
            const float tk = (t0 + t1) + (t2 + t3);
            float u = fmaxf(tk + bul, 0.f) * wol;
            #pragma unroll
            for (int off = 32; off > 0; off >>= 1)
                u += __shfl_xor(u, off);
            if (lane == 0) sarr[n] = u;
        }
        __syncthreads();
    }
}

// ---------------------------------------------------------------------------
// k_pool: per-graph mean-pool inputs. Wave-uniform fast path (batch sorted).
__global__ __launch_bounds__(256) void k_pool(
    const float* __restrict__ sarr, const int* __restrict__ batch,
    float* __restrict__ gsum, float* __restrict__ gcnt)
{
    __shared__ float ls[N_GRAPHS], lc[N_GRAPHS];
    const int t = threadIdx.x;
    if (t < N_GRAPHS) { ls[t] = 0.f; lc[t] = 0.f; }
    __syncthreads();

    const int n = blockIdx.x * blockDim.x + t;
    const int lane = t & 63;
    const bool valid = (n < N_NODES);
    float v = valid ? sarr[n] : 0.f;
    float cv = valid ? 1.f : 0.f;
    const int g = valid ? batch[n] : batch[N_NODES - 1];

    const int g0 = __shfl(g, 0);
    const bool uni = __all(g == g0);
    if (uni) {
        #pragma unroll
        for (int off = 32; off > 0; off >>= 1) {
            v  += __shfl_xor(v, off);
            cv += __shfl_xor(cv, off);
        }
        if (lane == 0 && cv != 0.f) {
            atomicAdd(&ls[g0], v);
            atomicAdd(&lc[g0], cv);
        }
    } else if (valid) {
        atomicAdd(&ls[g], v);
        atomicAdd(&lc[g], 1.f);
    }
    __syncthreads();
    if (t < N_GRAPHS && lc[t] != 0.f) {
        atomicAdd(&gsum[t], ls[t]);
        atomicAdd(&gcnt[t], lc[t]);
    }
}

// ---------------------------------------------------------------------------
__global__ void k_final(const float* __restrict__ gsum,
                        const float* __restrict__ gcnt,
                        const float* __restrict__ bo,
                        float* __restrict__ out)
{
    const int g = threadIdx.x;
    if (g < N_GRAPHS)
        out[g] = gsum[g] / fmaxf(gcnt[g], 1.f) + bo[0];
}

// ---------------------------------------------------------------------------
extern "C" void kernel_launch(void* const* d_in, const int* in_sizes, int n_in,
                              void* d_out, int out_size, void* d_ws, size_t ws_size,
                              hipStream_t stream)
{
    const float* x      = (const float*)d_in[0];
    const float* ea     = (const float*)d_in[1];
    const int*   ei     = (const int*)  d_in[2];
    const int*   batch  = (const int*)  d_in[3];
    const float* Wn     = (const float*)d_in[4];
    const float* bn     = (const float*)d_in[5];
    const float* We     = (const float*)d_in[6];
    const float* be     = (const float*)d_in[7];
    const float* Wm     = (const float*)d_in[8];
    const float* bm     = (const float*)d_in[9];
    const float* Wu     = (const float*)d_in[10];
    const float* bu     = (const float*)d_in[11];
    const float* Wo     = (const float*)d_in[12];
    const float* bo     = (const float*)d_in[13];

    float*  ws    = (float*)d_ws;
    float4* recs  = (float4*)(ws + REC_OFF);
    float2* pairs = (float2*)(ws + PAIRS_OFF);
    float*  sarr  = ws + SARR_OFF;
    int*    noff  = (int*)(ws + NOFF_OFF);
    int*    ncnt  = (int*)(ws + NCNT_OFF);
    float*  abc   = ws + ABC_OFF;
    float*  gsum  = ws + GSUM_OFF;
    float*  gcnt  = ws + GCNT_OFF;
    int*    hist  = (int*)(ws + HIST_OFF);
    int*    boff  = (int*)(ws + BOFF_OFF);
    int*    bcur  = (int*)(ws + BCUR_OFF);
    float*  out   = (float*)d_out;

    k_prep<<<1, 256, 0, stream>>>(hist, abc, gsum, gcnt, Wn, bn, We, be, Wm, bm);
    k_hist<<<128, 256, 0, stream>>>(ei, hist);
    k_scan<<<1, 512, 0, stream>>>(hist, boff, bcur);
    k_bin<<<NCHUNK, 256, 0, stream>>>(x, ea, ei, bcur, recs);
    k_fsort<<<NB, 256, 0, stream>>>(recs, boff, pairs, noff, ncnt);
    k_aggmv<<<AGG_BLOCKS, 256, 0, stream>>>(pairs, noff, ncnt, abc, Wu, bu, Wo, sarr);
    k_pool<<<(N_NODES + 255) / 256, 256, 0, stream>>>(sarr, batch, gsum, gcnt);
    k_final<<<1, 64, 0, stream>>>(gsum, gcnt, bo, out);
}

// Round 7
// 98.205 us; speedup vs baseline: 4.3426x; 1.0725x over previous
//
#include <hip/hip_runtime.h>

#define N_NODES 50000
#define N_EDGES 800000
#define N_GRAPHS 64
#define H 64
#define BN 128                                   // nodes per bucket
#define NB ((N_NODES + BN - 1) / BN)             // 391
#define CHUNK 2048
#define NCHUNK ((N_EDGES + CHUNK - 1) / CHUNK)   // 391
#define STAGE 2560                               // k_fsort LDS stage (float2)

#define AGG_BLOCKS 2048

// ws layout (float units)
#define REC_OFF   0                              // float4[N_EDGES] = 12.8 MB
#define PAIRS_OFF (4 * N_EDGES)                  // float2[N_EDGES] = 6.4 MB
#define SARR_OFF  (PAIRS_OFF + 2 * N_EDGES)      // float[N_NODES]
#define NOFF_OFF  (SARR_OFF + N_NODES)           // int[N_NODES]
#define NCNT_OFF  (NOFF_OFF + N_NODES)           // int[N_NODES]
#define ABC_OFF   (NCNT_OFF + N_NODES)           // float[3*H]
#define GSUM_OFF  (ABC_OFF + 3 * H)
#define GCNT_OFF  (GSUM_OFF + N_GRAPHS)
#define HIST_OFF  (GCNT_OFF + N_GRAPHS)          // int[NB]
#define BOFF_OFF  (HIST_OFF + NB)                // int[NB+1]
#define BCUR_OFF  (BOFF_OFF + NB + 1)            // int[NB]

__device__ __forceinline__ float rdlane(float v, int l) {
    return __int_as_float(__builtin_amdgcn_readlane(__float_as_int(v), l));
}

// ---------------------------------------------------------------------------
__global__ __launch_bounds__(256) void k_prep(
    int* __restrict__ hist, float* __restrict__ abc,
    float* __restrict__ gsum, float* __restrict__ gcnt,
    const float* __restrict__ Wn, const float* __restrict__ bn,
    const float* __restrict__ We, const float* __restrict__ be,
    const float* __restrict__ Wm, const float* __restrict__ bm)
{
    const int t = threadIdx.x;
    for (int i = t; i < NB; i += 256) hist[i] = 0;
    if (t < N_GRAPHS) { gsum[t] = 0.f; gcnt[t] = 0.f; }
    if (t < H) {
        const int k = t;
        float a = 0.f, b = 0.f, c = 0.f;
        #pragma unroll
        for (int i = 0; i < H; ++i) {
            float wt = Wm[i * H + k];
            float wb = Wm[(H + i) * H + k];
            a = fmaf(Wn[i], wt, a);
            b = fmaf(We[i], wb, b);
            c = fmaf(bn[i], wt, c);
            c = fmaf(be[i], wb, c);
        }
        abc[k]         = a;
        abc[H + k]     = b;
        abc[2 * H + k] = c + bm[k];
    }
}

// ---------------------------------------------------------------------------
__global__ __launch_bounds__(256) void k_hist(
    const int* __restrict__ ei, int* __restrict__ hist)
{
    __shared__ int lh[NB];
    const int t = threadIdx.x;
    for (int b = t; b < NB; b += 256) lh[b] = 0;
    __syncthreads();
    const int* __restrict__ dst = ei + N_EDGES;
    const int tid = blockIdx.x * blockDim.x + threadIdx.x;
    const int nthreads = gridDim.x * blockDim.x;
    for (int e = tid; e < N_EDGES; e += nthreads)
        atomicAdd(&lh[dst[e] >> 7], 1);
    __syncthreads();
    for (int b = t; b < NB; b += 256) {
        const int v = lh[b];
        if (v) atomicAdd(&hist[b], v);
    }
}

// ---------------------------------------------------------------------------
__global__ __launch_bounds__(512) void k_scan(
    const int* __restrict__ hist, int* __restrict__ boff, int* __restrict__ bcur)
{
    __shared__ int s[512];
    const int t = threadIdx.x;
    const int v = (t < NB) ? hist[t] : 0;
    s[t] = v;
    __syncthreads();
    #pragma unroll
    for (int d = 1; d < 512; d <<= 1) {
        const int add = (t >= d) ? s[t - d] : 0;
        __syncthreads();
        s[t] += add;
        __syncthreads();
    }
    if (t == 0) boff[0] = 0;
    if (t < NB) {
        boff[t + 1] = s[t];
        bcur[t]     = s[t] - v;
    }
}

// ---------------------------------------------------------------------------
// k_bin: staged coarse scatter (one contiguous run per WG per bucket).
__global__ __launch_bounds__(256) void k_bin(
    const float* __restrict__ x, const float* __restrict__ ea,
    const int* __restrict__ ei, int* __restrict__ bcur,
    float4* __restrict__ recs)
{
    __shared__ int lh[NB], lbase[NB], lcur[NB];
    const int t = threadIdx.x;
    for (int b = t; b < NB; b += 256) { lh[b] = 0; lcur[b] = 0; }
    __syncthreads();

    const int e0 = blockIdx.x * CHUNK;
    const int* __restrict__ src = ei;
    const int* __restrict__ dst = ei + N_EDGES;

    for (int i = t; i < CHUNK; i += 256) {
        const int e = e0 + i;
        if (e < N_EDGES) atomicAdd(&lh[dst[e] >> 7], 1);
    }
    __syncthreads();
    for (int b = t; b < NB; b += 256) {
        const int v = lh[b];
        if (v) lbase[b] = atomicAdd(&bcur[b], v);
    }
    __syncthreads();
    for (int i = t; i < CHUNK; i += 256) {
        const int e = e0 + i;
        if (e < N_EDGES) {
            const int d = dst[e];
            const int b = d >> 7;
            const int lp = atomicAdd(&lcur[b], 1);
            recs[lbase[b] + lp] =
                make_float4(x[src[e]], ea[e], __int_as_float(d & (BN - 1)), 0.f);
        }
    }
}

// ---------------------------------------------------------------------------
// k_fsort: per-bucket node sort; pairs staged in LDS then flushed coalesced.
__global__ __launch_bounds__(256) void k_fsort(
    const float4* __restrict__ recs, const int* __restrict__ boff,
    float2* __restrict__ pairs,
    int* __restrict__ noff, int* __restrict__ ncnt)
{
    __shared__ int lh[BN], le[BN], lc[BN];
    __shared__ float2 st2[STAGE];
    const int t = threadIdx.x;
    const int b = blockIdx.x;
    if (t < BN) lh[t] = 0;
    __syncthreads();

    const int st = boff[b];
    const int m  = boff[b + 1] - st;

    for (int i = t; i < m; i += 256)
        atomicAdd(&lh[__float_as_int(recs[st + i].z)], 1);
    __syncthreads();

    if (t < BN) le[t] = lh[t];
    __syncthreads();
    #pragma unroll
    for (int d = 1; d < BN; d <<= 1) {
        const int add = (t >= d && t < BN) ? le[t - d] : 0;
        __syncthreads();
        if (t < BN) le[t] += add;
        __syncthreads();
    }
    if (t < BN) {
        const int excl = le[t] - lh[t];
        lc[t] = excl;
        const int node = b * BN + t;
        if (node < N_NODES) {
            noff[node] = st + excl;
            ncnt[node] = lh[t];
        }
    }
    __syncthreads();

    if (m <= STAGE) {
        for (int i = t; i < m; i += 256) {
            const float4 r = recs[st + i];
            const int rk = atomicAdd(&lc[__float_as_int(r.z)], 1);
            st2[rk] = make_float2(r.x, r.y);
        }
        __syncthreads();
        for (int i = t; i < m; i += 256)
            pairs[st + i] = st2[i];
    } else {
        for (int i = t; i < m; i += 256) {
            const float4 r = recs[st + i];
            const int rk = atomicAdd(&lc[__float_as_int(r.z)], 1);
            pairs[st + rk] = make_float2(r.x, r.y);
        }
    }
}

// ---------------------------------------------------------------------------
// k_aggmv: one wave per node, grid-stride, NO LDS, NO barriers.
// Phase A: coalesced batch load of the node's edge pairs + readlane broadcast.
// Phase B: Wu column k held in 64 registers; a[i] via compile-time readlane.
__global__ __launch_bounds__(256) void k_aggmv(
    const float2* __restrict__ pairs, const int* __restrict__ noff,
    const int* __restrict__ ncnt, const float* __restrict__ abc,
    const float* __restrict__ Wu, const float* __restrict__ bu,
    const float* __restrict__ Wo, float* __restrict__ sarr)
{
    const int t    = threadIdx.x;
    const int lane = t & 63;
    const int gw   = (blockIdx.x * blockDim.x + t) >> 6;
    const int nw   = (gridDim.x * blockDim.x) >> 6;

    const float A   = abc[lane];
    const float B   = abc[H + lane];
    const float C   = abc[2 * H + lane];
    const float bul = bu[lane];
    const float wol = Wo[lane];

    // Wu column `lane` into registers (coalesced; L1-resident after 1st wave)
    float wr[64];
    #pragma unroll
    for (int i = 0; i < 64; ++i) wr[i] = Wu[i * H + lane];

    for (int n = gw; n < N_NODES; n += nw) {
        const int st = noff[n];
        const int c  = ncnt[n];

        // ---- phase A: aggregate component `lane` over the node's edges
        float s = 0.f;
        for (int j0 = 0; j0 < c; j0 += 64) {
            const int rem = c - j0;
            float2 p = make_float2(0.f, 0.f);
            if (lane < rem) p = pairs[st + j0 + lane];
            const int cnt = min(64, rem);
            for (int j = 0; j < cnt; ++j) {
                const float xj = rdlane(p.x, j);
                const float ej = rdlane(p.y, j);
                s += fmaxf(fmaf(xj, A, fmaf(ej, B, C)), 0.f);
            }
        }

        // ---- phase B: t_k = sum_i a[i] * Wu[i][k], a[i] broadcast by readlane
        float t0 = 0.f, t1 = 0.f, t2 = 0.f, t3 = 0.f;
        #pragma unroll
        for (int i = 0; i < 64; i += 4) {
            t0 = fmaf(rdlane(s, i + 0), wr[i + 0], t0);
            t1 = fmaf(rdlane(s, i + 1), wr[i + 1], t1);
            t2 = fmaf(rdlane(s, i + 2), wr[i + 2], t2);
            t3 = fmaf(rdlane(s, i + 3), wr[i + 3], t3);
        }
        const float tk = (t0 + t1) + (t2 + t3);
        float u = fmaxf(tk + bul, 0.f) * wol;
        #pragma unroll
        for (int off = 32; off > 0; off >>= 1)
            u += __shfl_xor(u, off);
        if (lane == 0) sarr[n] = u;
    }
}

// ---------------------------------------------------------------------------
// k_pool: per-graph mean-pool inputs. Wave-uniform fast path (batch sorted).
__global__ __launch_bounds__(256) void k_pool(
    const float* __restrict__ sarr, const int* __restrict__ batch,
    float* __restrict__ gsum, float* __restrict__ gcnt)
{
    __shared__ float ls[N_GRAPHS], lc[N_GRAPHS];
    const int t = threadIdx.x;
    if (t < N_GRAPHS) { ls[t] = 0.f; lc[t] = 0.f; }
    __syncthreads();

    const int n = blockIdx.x * blockDim.x + t;
    const int lane = t & 63;
    const bool valid = (n < N_NODES);
    float v = valid ? sarr[n] : 0.f;
    float cv = valid ? 1.f : 0.f;
    const int g = valid ? batch[n] : batch[N_NODES - 1];

    const int g0 = __shfl(g, 0);
    const bool uni = __all(g == g0);
    if (uni) {
        #pragma unroll
        for (int off = 32; off > 0; off >>= 1) {
            v  += __shfl_xor(v, off);
            cv += __shfl_xor(cv, off);
        }
        if (lane == 0 && cv != 0.f) {
            atomicAdd(&ls[g0], v);
            atomicAdd(&lc[g0], cv);
        }
    } else if (valid) {
        atomicAdd(&ls[g], v);
        atomicAdd(&lc[g], 1.f);
    }
    __syncthreads();
    if (t < N_GRAPHS && lc[t] != 0.f) {
        atomicAdd(&gsum[t], ls[t]);
        atomicAdd(&gcnt[t], lc[t]);
    }
}

// ---------------------------------------------------------------------------
__global__ void k_final(const float* __restrict__ gsum,
                        const float* __restrict__ gcnt,
                        const float* __restrict__ bo,
                        float* __restrict__ out)
{
    const int g = threadIdx.x;
    if (g < N_GRAPHS)
        out[g] = gsum[g] / fmaxf(gcnt[g], 1.f) + bo[0];
}

// ---------------------------------------------------------------------------
extern "C" void kernel_launch(void* const* d_in, const int* in_sizes, int n_in,
                              void* d_out, int out_size, void* d_ws, size_t ws_size,
                              hipStream_t stream)
{
    const float* x      = (const float*)d_in[0];
    const float* ea     = (const float*)d_in[1];
    const int*   ei     = (const int*)  d_in[2];
    const int*   batch  = (const int*)  d_in[3];
    const float* Wn     = (const float*)d_in[4];
    const float* bn     = (const float*)d_in[5];
    const float* We     = (const float*)d_in[6];
    const float* be     = (const float*)d_in[7];
    const float* Wm     = (const float*)d_in[8];
    const float* bm     = (const float*)d_in[9];
    const float* Wu     = (const float*)d_in[10];
    const float* bu     = (const float*)d_in[11];
    const float* Wo     = (const float*)d_in[12];
    const float* bo     = (const float*)d_in[13];

    float*  ws    = (float*)d_ws;
    float4* recs  = (float4*)(ws + REC_OFF);
    float2* pairs = (float2*)(ws + PAIRS_OFF);
    float*  sarr  = ws + SARR_OFF;
    int*    noff  = (int*)(ws + NOFF_OFF);
    int*    ncnt  = (int*)(ws + NCNT_OFF);
    float*  abc   = ws + ABC_OFF;
    float*  gsum  = ws + GSUM_OFF;
    float*  gcnt  = ws + GCNT_OFF;
    int*    hist  = (int*)(ws + HIST_OFF);
    int*    boff  = (int*)(ws + BOFF_OFF);
    int*    bcur  = (int*)(ws + BCUR_OFF);
    float*  out   = (float*)d_out;

    k_prep<<<1, 256, 0, stream>>>(hist, abc, gsum, gcnt, Wn, bn, We, be, Wm, bm);
    k_hist<<<128, 256, 0, stream>>>(ei, hist);
    k_scan<<<1, 512, 0, stream>>>(hist, boff, bcur);
    k_bin<<<NCHUNK, 256, 0, stream>>>(x, ea, ei, bcur, recs);
    k_fsort<<<NB, 256, 0, stream>>>(recs, boff, pairs, noff, ncnt);
    k_aggmv<<<AGG_BLOCKS, 256, 0, stream>>>(pairs, noff, ncnt, abc, Wu, bu, Wo, sarr);
    k_pool<<<(N_NODES + 255) / 256, 256, 0, stream>>>(sarr, batch, gsum, gcnt);
    k_final<<<1, 64, 0, stream>>>(gsum, gcnt, bo, out);
}

// Round 8
// 87.222 us; speedup vs baseline: 4.8894x; 1.1259x over previous
//
#include <hip/hip_runtime.h>

#define N_NODES 50000
#define N_EDGES 800000
#define N_GRAPHS 64
#define H 64
#define BN 128                                   // nodes per bucket
#define NB ((N_NODES + BN - 1) / BN)             // 391
#define CAP 2432                                 // max records per bucket (mean 2046 + 8.5 sigma)
#define CHUNK 2048
#define NCHUNK ((N_EDGES + CHUNK - 1) / CHUNK)   // 391

// ws layout (float units)
// region A: union{ [vals float2 NB*CAP][ldst u8 NB*CAP] } then reused as aggr[N_NODES*H]
#define VALS_OFF  0                              // float2[NB*CAP]  (7.6 MB)
#define LDST_OFF  (NB * CAP * 2)                 // u8[NB*CAP] viewed as floats
#define AGGR_OFF  0                              // float[N_NODES*H] = 12.8 MB (aliases vals+ldst)
#define PAIRS_OFF (N_NODES * H)                  // float2[NB*CAP] (7.6 MB)
#define SARR_OFF  (PAIRS_OFF + NB * CAP * 2)     // float[N_NODES]
#define NOFF_OFF  (SARR_OFF + N_NODES)           // int[N_NODES]
#define NCNT_OFF  (NOFF_OFF + N_NODES)           // int[N_NODES]
#define ABC_OFF   (NCNT_OFF + N_NODES)           // float[3*H]
#define GSUM_OFF  (ABC_OFF + 3 * H)
#define GCNT_OFF  (GSUM_OFF + N_GRAPHS)
#define BCUR_OFF  (GCNT_OFF + N_GRAPHS)          // int[NB]

// ---------------------------------------------------------------------------
__global__ __launch_bounds__(256) void k_prep(
    int* __restrict__ bcur, float* __restrict__ abc,
    float* __restrict__ gsum, float* __restrict__ gcnt,
    const float* __restrict__ Wn, const float* __restrict__ bn,
    const float* __restrict__ We, const float* __restrict__ be,
    const float* __restrict__ Wm, const float* __restrict__ bm)
{
    const int t = threadIdx.x;
    for (int i = t; i < NB; i += 256) bcur[i] = 0;
    if (t < N_GRAPHS) { gsum[t] = 0.f; gcnt[t] = 0.f; }
    if (t < H) {
        const int k = t;
        float a = 0.f, b = 0.f, c = 0.f;
        #pragma unroll
        for (int i = 0; i < H; ++i) {
            float wt = Wm[i * H + k];
            float wb = Wm[(H + i) * H + k];
            a = fmaf(Wn[i], wt, a);
            b = fmaf(We[i], wb, b);
            c = fmaf(bn[i], wt, c);
            c = fmaf(be[i], wb, c);
        }
        abc[k]         = a;
        abc[H + k]     = b;
        abc[2 * H + k] = c + bm[k];
    }
}

// ---------------------------------------------------------------------------
// k_bin: staged coarse scatter into fixed-capacity bucket regions.
// One contiguous run per (WG,bucket) -> L2 merges the writes.
__global__ __launch_bounds__(256) void k_bin(
    const float* __restrict__ x, const float* __restrict__ ea,
    const int* __restrict__ ei, int* __restrict__ bcur,
    float2* __restrict__ vals, unsigned char* __restrict__ ldst)
{
    __shared__ int lh[NB], lbase[NB], lcur[NB];
    const int t = threadIdx.x;
    for (int b = t; b < NB; b += 256) { lh[b] = 0; lcur[b] = 0; }
    __syncthreads();

    const int e0 = blockIdx.x * CHUNK;
    const int* __restrict__ src = ei;
    const int* __restrict__ dst = ei + N_EDGES;

    for (int i = t; i < CHUNK; i += 256) {
        const int e = e0 + i;
        if (e < N_EDGES) atomicAdd(&lh[dst[e] >> 7], 1);
    }
    __syncthreads();
    for (int b = t; b < NB; b += 256) {
        const int v = lh[b];
        if (v) lbase[b] = atomicAdd(&bcur[b], v);
    }
    __syncthreads();
    for (int i = t; i < CHUNK; i += 256) {
        const int e = e0 + i;
        if (e < N_EDGES) {
            const int d = dst[e];
            const int b = d >> 7;
            const int lp = atomicAdd(&lcur[b], 1);
            const int idx = b * CAP + lbase[b] + lp;
            vals[idx] = make_float2(x[src[e]], ea[e]);
            ldst[idx] = (unsigned char)(d & (BN - 1));
        }
    }
}

// ---------------------------------------------------------------------------
// k_fsort: per-bucket node sort; output staged in LDS, flushed coalesced.
__global__ __launch_bounds__(256) void k_fsort(
    const float2* __restrict__ vals, const unsigned char* __restrict__ ldst,
    const int* __restrict__ bcur, float2* __restrict__ pairs,
    int* __restrict__ noff, int* __restrict__ ncnt)
{
    __shared__ int lh[BN], le[BN], lc[BN];
    __shared__ float2 st2[CAP];
    const int t = threadIdx.x;
    const int b = blockIdx.x;
    const int base = b * CAP;
    int m = bcur[b];
    if (m > CAP) m = CAP;            // defensive (overflow would fail validation anyway)
    if (t < BN) lh[t] = 0;
    __syncthreads();

    for (int i = t; i < m; i += 256)
        atomicAdd(&lh[ldst[base + i]], 1);
    __syncthreads();

    if (t < BN) le[t] = lh[t];
    __syncthreads();
    #pragma unroll
    for (int d = 1; d < BN; d <<= 1) {
        const int add = (t >= d && t < BN) ? le[t - d] : 0;
        __syncthreads();
        if (t < BN) le[t] += add;
        __syncthreads();
    }
    if (t < BN) {
        const int excl = le[t] - lh[t];
        lc[t] = excl;
        const int node = b * BN + t;
        if (node < N_NODES) {
            noff[node] = base + excl;
            ncnt[node] = lh[t];
        }
    }
    __syncthreads();

    for (int i = t; i < m; i += 256) {
        const float2 r = vals[base + i];
        const int rk = atomicAdd(&lc[ldst[base + i]], 1);
        st2[rk] = r;
    }
    __syncthreads();
    for (int i = t; i < m; i += 256)
        pairs[base + i] = st2[i];
}

// ---------------------------------------------------------------------------
// k_aggr: wave-per-node, lane k = component k. Edge scalars come in via
// wave-uniform loads (HW broadcast, 1 transaction) — no readlane. 4 partial
// accumulators break the serial add chain.
__global__ __launch_bounds__(256) void k_aggr(
    const float2* __restrict__ pairs, const int* __restrict__ noff,
    const int* __restrict__ ncnt, const float* __restrict__ abc,
    float* __restrict__ aggr)
{
    const int t    = threadIdx.x;
    const int lane = t & 63;
    const int gw   = (blockIdx.x * blockDim.x + t) >> 6;
    const int nw   = (gridDim.x * blockDim.x) >> 6;

    const float A = abc[lane];
    const float B = abc[H + lane];
    const float C = abc[2 * H + lane];

    #define MSG(q) fmaxf(fmaf((q).x, A, fmaf((q).y, B, C)), 0.f)

    for (int n = gw; n < N_NODES; n += nw) {
        const int st = noff[n];
        const int c  = ncnt[n];
        const float2* __restrict__ pp = pairs + st;

        float s0 = 0.f, s1 = 0.f, s2 = 0.f, s3 = 0.f;
        int j = 0;
        for (; j + 8 <= c; j += 8) {
            const float2 q0 = pp[j + 0], q1 = pp[j + 1], q2 = pp[j + 2], q3 = pp[j + 3];
            const float2 q4 = pp[j + 4], q5 = pp[j + 5], q6 = pp[j + 6], q7 = pp[j + 7];
            s0 += MSG(q0); s1 += MSG(q1); s2 += MSG(q2); s3 += MSG(q3);
            s0 += MSG(q4); s1 += MSG(q5); s2 += MSG(q6); s3 += MSG(q7);
        }
        for (; j < c; ++j) {
            const float2 q = pp[j];
            s0 += MSG(q);
        }
        aggr[(size_t)n * H + lane] = (s0 + s1) + (s2 + s3);
    }
    #undef MSG
}

// ---------------------------------------------------------------------------
// k_mv: wave-per-node matvec. Wu column `lane` in 64 VGPRs (loaded once);
// aggregate row via wave-uniform base -> scalar loads feed fma directly.
__global__ __launch_bounds__(256) void k_mv(
    const float* __restrict__ aggr, const float* __restrict__ Wu,
    const float* __restrict__ bu, const float* __restrict__ Wo,
    float* __restrict__ sarr)
{
    const int t    = threadIdx.x;
    const int lane = t & 63;
    const int gw   = (blockIdx.x * blockDim.x + t) >> 6;
    const int nw   = (gridDim.x * blockDim.x) >> 6;

    float wr[64];
    #pragma unroll
    for (int i = 0; i < 64; ++i) wr[i] = Wu[i * H + lane];
    const float bul = bu[lane];
    const float wol = Wo[lane];

    for (int n = gw; n < N_NODES; n += nw) {
        const int nu = __builtin_amdgcn_readfirstlane(n);
        const float* __restrict__ row = aggr + (size_t)nu * H;

        float t0 = 0.f, t1 = 0.f, t2 = 0.f, t3 = 0.f;
        #pragma unroll
        for (int i = 0; i < 64; i += 4) {
            t0 = fmaf(row[i + 0], wr[i + 0], t0);
            t1 = fmaf(row[i + 1], wr[i + 1], t1);
            t2 = fmaf(row[i + 2], wr[i + 2], t2);
            t3 = fmaf(row[i + 3], wr[i + 3], t3);
        }
        const float tk = (t0 + t1) + (t2 + t3);
        float u = fmaxf(tk + bul, 0.f) * wol;
        #pragma unroll
        for (int off = 32; off > 0; off >>= 1)
            u += __shfl_xor(u, off);
        if (lane == 0) sarr[nu] = u;
    }
}

// ---------------------------------------------------------------------------
// k_pool: per-graph mean-pool. Wave-uniform fast path (batch sorted).
__global__ __launch_bounds__(256) void k_pool(
    const float* __restrict__ sarr, const int* __restrict__ batch,
    float* __restrict__ gsum, float* __restrict__ gcnt)
{
    __shared__ float ls[N_GRAPHS], lc[N_GRAPHS];
    const int t = threadIdx.x;
    if (t < N_GRAPHS) { ls[t] = 0.f; lc[t] = 0.f; }
    __syncthreads();

    const int n = blockIdx.x * blockDim.x + t;
    const int lane = t & 63;
    const bool valid = (n < N_NODES);
    float v  = valid ? sarr[n] : 0.f;
    float cv = valid ? 1.f : 0.f;
    const int g = valid ? batch[n] : batch[N_NODES - 1];

    const int g0 = __shfl(g, 0);
    const bool uni = __all(g == g0);
    if (uni) {
        #pragma unroll
        for (int off = 32; off > 0; off >>= 1) {
            v  += __shfl_xor(v, off);
            cv += __shfl_xor(cv, off);
        }
        if (lane == 0 && cv != 0.f) {
            atomicAdd(&ls[g0], v);
            atomicAdd(&lc[g0], cv);
        }
    } else if (valid) {
        atomicAdd(&ls[g], v);
        atomicAdd(&lc[g], 1.f);
    }
    __syncthreads();
    if (t < N_GRAPHS && lc[t] != 0.f) {
        atomicAdd(&gsum[t], ls[t]);
        atomicAdd(&gcnt[t], lc[t]);
    }
}

// ---------------------------------------------------------------------------
__global__ void k_final(const float* __restrict__ gsum,
                        const float* __restrict__ gcnt,
                        const float* __restrict__ bo,
                        float* __restrict__ out)
{
    const int g = threadIdx.x;
    if (g < N_GRAPHS)
        out[g] = gsum[g] / fmaxf(gcnt[g], 1.f) + bo[0];
}

// ---------------------------------------------------------------------------
extern "C" void kernel_launch(void* const* d_in, const int* in_sizes, int n_in,
                              void* d_out, int out_size, void* d_ws, size_t ws_size,
                              hipStream_t stream)
{
    const float* x      = (const float*)d_in[0];
    const float* ea     = (const float*)d_in[1];
    const int*   ei     = (const int*)  d_in[2];
    const int*   batch  = (const int*)  d_in[3];
    const float* Wn     = (const float*)d_in[4];
    const float* bn     = (const float*)d_in[5];
    const float* We     = (const float*)d_in[6];
    const float* be     = (const float*)d_in[7];
    const float* Wm     = (const float*)d_in[8];
    const float* bm     = (const float*)d_in[9];
    const float* Wu     = (const float*)d_in[10];
    const float* bu     = (const float*)d_in[11];
    const float* Wo     = (const float*)d_in[12];
    const float* bo     = (const float*)d_in[13];

    float*  ws    = (float*)d_ws;
    float2* vals  = (float2*)(ws + VALS_OFF);
    unsigned char* ldst = (unsigned char*)(ws + LDST_OFF);
    float*  aggr  = ws + AGGR_OFF;              // aliases vals/ldst (stream-ordered)
    float2* pairs = (float2*)(ws + PAIRS_OFF);
    float*  sarr  = ws + SARR_OFF;
    int*    noff  = (int*)(ws + NOFF_OFF);
    int*    ncnt  = (int*)(ws + NCNT_OFF);
    float*  abc   = ws + ABC_OFF;
    float*  gsum  = ws + GSUM_OFF;
    float*  gcnt  = ws + GCNT_OFF;
    int*    bcur  = (int*)(ws + BCUR_OFF);
    float*  out   = (float*)d_out;

    k_prep<<<1, 256, 0, stream>>>(bcur, abc, gsum, gcnt, Wn, bn, We, be, Wm, bm);
    k_bin<<<NCHUNK, 256, 0, stream>>>(x, ea, ei, bcur, vals, ldst);
    k_fsort<<<NB, 256, 0, stream>>>(vals, ldst, bcur, pairs, noff, ncnt);
    k_aggr<<<2048, 256, 0, stream>>>(pairs, noff, ncnt, abc, aggr);
    k_mv<<<1024, 256, 0, stream>>>(aggr, Wu, bu, Wo, sarr);
    k_pool<<<(N_NODES + 255) / 256, 256, 0, stream>>>(sarr, batch, gsum, gcnt);
    k_final<<<1, 64, 0, stream>>>(gsum, gcnt, bo, out);
}

// Round 9
// 64.143 us; speedup vs baseline: 6.6486x; 1.3598x over previous
//
#include <hip/hip_runtime.h>

#define N_NODES 50000
#define N_EDGES 800000
#define N_GRAPHS 64
#define H 64
#define BN 64                                    // nodes per bucket
#define NB ((N_NODES + BN - 1) / BN)             // 782
#define CAP 1280                                 // max records/bucket (mean 1023 + 8 sigma)
#define CHUNK 4096
#define NCHUNK ((N_EDGES + CHUNK - 1) / CHUNK)   // 196

// ws layout (float units)
#define VALS_OFF  0                              // float2[NB*CAP] = 8.0 MB
#define ABC_OFF   (NB * CAP * 2)
#define GSUM_OFF  (ABC_OFF + 3 * H)
#define GCNT_OFF  (GSUM_OFF + N_GRAPHS)
#define BCUR_OFF  (GCNT_OFF + N_GRAPHS)          // int[NB]

// ---------------------------------------------------------------------------
__global__ __launch_bounds__(256) void k_prep(
    int* __restrict__ bcur, float* __restrict__ abc,
    float* __restrict__ gsum, float* __restrict__ gcnt,
    const float* __restrict__ Wn, const float* __restrict__ bn,
    const float* __restrict__ We, const float* __restrict__ be,
    const float* __restrict__ Wm, const float* __restrict__ bm)
{
    const int t = threadIdx.x;
    for (int i = t; i < NB; i += 256) bcur[i] = 0;
    if (t < N_GRAPHS) { gsum[t] = 0.f; gcnt[t] = 0.f; }
    if (t < H) {
        const int k = t;
        float a = 0.f, b = 0.f, c = 0.f;
        #pragma unroll
        for (int i = 0; i < H; ++i) {
            float wt = Wm[i * H + k];
            float wb = Wm[(H + i) * H + k];
            a = fmaf(Wn[i], wt, a);
            b = fmaf(We[i], wb, b);
            c = fmaf(bn[i], wt, c);
            c = fmaf(be[i], wb, c);
        }
        abc[k]         = a;
        abc[H + k]     = b;
        abc[2 * H + k] = c + bm[k];
    }
}

// ---------------------------------------------------------------------------
// k_bin: staged coarse scatter into fixed-capacity bucket regions.
// Local dst (6 bits) is packed into ea's low mantissa bits (rel err ~7.5e-6).
__global__ __launch_bounds__(256) void k_bin(
    const float* __restrict__ x, const float* __restrict__ ea,
    const int* __restrict__ ei, int* __restrict__ bcur,
    float2* __restrict__ vals)
{
    __shared__ int lh[NB], lbase[NB], lcur[NB];
    const int t = threadIdx.x;
    for (int b = t; b < NB; b += 256) { lh[b] = 0; lcur[b] = 0; }
    __syncthreads();

    const int e0 = blockIdx.x * CHUNK;
    const int* __restrict__ src = ei;
    const int* __restrict__ dst = ei + N_EDGES;

    for (int i = t; i < CHUNK; i += 256) {
        const int e = e0 + i;
        if (e < N_EDGES) atomicAdd(&lh[dst[e] >> 6], 1);
    }
    __syncthreads();
    for (int b = t; b < NB; b += 256) {
        const int v = lh[b];
        if (v) lbase[b] = atomicAdd(&bcur[b], v);
    }
    __syncthreads();
    for (int i = t; i < CHUNK; i += 256) {
        const int e = e0 + i;
        if (e < N_EDGES) {
            const int d = dst[e];
            const int b = d >> 6;
            const int lp = atomicAdd(&lcur[b], 1);
            const unsigned uy = (__float_as_uint(ea[e]) & 0xFFFFFFC0u) |
                                (unsigned)(d & (BN - 1));
            vals[b * CAP + lbase[b] + lp] = make_float2(x[src[e]], __uint_as_float(uy));
        }
    }
}

// ---------------------------------------------------------------------------
// k_fused: per bucket — load+hist records into LDS, wave-scan 64 bins,
// in-LDS node sort, then per-wave: aggregate 16 nodes (uniform LDS reads),
// matvec with Wu column in VGPRs + aggregate row via uniform ds_read_b128,
// ReLU-dot, shfl-reduce, pool into LDS graph bins -> global atomics.
__global__ __launch_bounds__(256) void k_fused(
    const float2* __restrict__ vals, const int* __restrict__ bcur,
    const float* __restrict__ abc, const float* __restrict__ Wu,
    const float* __restrict__ bu, const float* __restrict__ Wo,
    const int* __restrict__ batch,
    float* __restrict__ gsum, float* __restrict__ gcnt)
{
    __shared__ float2 stA[CAP];                 // raw records      (10.24 KB)
    __shared__ float2 stB[CAP];                 // node-sorted      (10.24 KB)
    __shared__ int lh[BN], le[BN], lc[BN];
    __shared__ __align__(16) float sA[4][72];   // per-wave aggregate row
    __shared__ float lsum[N_GRAPHS], lcnt[N_GRAPHS];

    const int t    = threadIdx.x;
    const int lane = t & 63;
    const int w    = t >> 6;
    const int b    = blockIdx.x;
    const int base = b * CAP;

    // per-lane constants + Wu column `lane` in registers (overlaps LDS init)
    const float A   = abc[lane];
    const float B   = abc[H + lane];
    const float C   = abc[2 * H + lane];
    const float bul = bu[lane];
    const float wol = Wo[lane];
    float wr[64];
    #pragma unroll
    for (int i = 0; i < 64; ++i) wr[i] = Wu[i * H + lane];

    if (t < BN) lh[t] = 0;
    if (t < N_GRAPHS) { lsum[t] = 0.f; lcnt[t] = 0.f; }
    __syncthreads();

    int m = bcur[b];
    if (m > CAP) m = CAP;

    // load + histogram
    for (int i = t; i < m; i += 256) {
        const float2 r = vals[base + i];
        stA[i] = r;
        atomicAdd(&lh[__float_as_uint(r.y) & (BN - 1)], 1);
    }
    __syncthreads();

    // exclusive scan of 64 bins (wave 0, shuffle scan)
    if (t < BN) {
        const int v = lh[t];
        int incl = v;
        #pragma unroll
        for (int d = 1; d < BN; d <<= 1) {
            const int up = __shfl_up(incl, d);
            if (lane >= d) incl += up;
        }
        le[t] = incl - v;
        lc[t] = incl - v;
    }
    __syncthreads();

    // in-LDS sort
    for (int i = t; i < m; i += 256) {
        const float2 r = stA[i];
        const int rk = atomicAdd(&lc[__float_as_uint(r.y) & (BN - 1)], 1);
        stB[rk] = r;
    }
    __syncthreads();

    // per-wave: 16 nodes each
    #define MSG(q) fmaxf(fmaf((q).x, A, fmaf((q).y, B, C)), 0.f)
    for (int qn = 0; qn < BN / 4; ++qn) {
        const int ln   = w * (BN / 4) + qn;
        const int node = b * BN + ln;
        const int off  = le[ln];
        const int c    = lh[ln];

        float s0 = 0.f, s1 = 0.f, s2 = 0.f, s3 = 0.f;
        int j = 0;
        for (; j + 8 <= c; j += 8) {
            const float2 q0 = stB[off + j + 0], q1 = stB[off + j + 1];
            const float2 q2 = stB[off + j + 2], q3 = stB[off + j + 3];
            const float2 q4 = stB[off + j + 4], q5 = stB[off + j + 5];
            const float2 q6 = stB[off + j + 6], q7 = stB[off + j + 7];
            s0 += MSG(q0); s1 += MSG(q1); s2 += MSG(q2); s3 += MSG(q3);
            s0 += MSG(q4); s1 += MSG(q5); s2 += MSG(q6); s3 += MSG(q7);
        }
        for (; j < c; ++j) { const float2 q = stB[off + j]; s0 += MSG(q); }
        const float s = (s0 + s1) + (s2 + s3);

        // matvec: row to LDS, uniform float4 reads broadcast a[i]
        sA[w][lane] = s;
        float t0 = 0.f, t1 = 0.f, t2 = 0.f, t3 = 0.f;
        #pragma unroll
        for (int i = 0; i < 64; i += 4) {
            const float4 av = *(const float4*)&sA[w][i];
            t0 = fmaf(av.x, wr[i + 0], t0);
            t1 = fmaf(av.y, wr[i + 1], t1);
            t2 = fmaf(av.z, wr[i + 2], t2);
            t3 = fmaf(av.w, wr[i + 3], t3);
        }
        const float tk = (t0 + t1) + (t2 + t3);
        float u = fmaxf(tk + bul, 0.f) * wol;
        #pragma unroll
        for (int off2 = 32; off2 > 0; off2 >>= 1)
            u += __shfl_xor(u, off2);
        if (lane == 0 && node < N_NODES) {
            const int g = batch[node];
            atomicAdd(&lsum[g], u);
            atomicAdd(&lcnt[g], 1.f);
        }
    }
    #undef MSG
    __syncthreads();
    if (t < N_GRAPHS && lcnt[t] != 0.f) {
        atomicAdd(&gsum[t], lsum[t]);
        atomicAdd(&gcnt[t], lcnt[t]);
    }
}

// ---------------------------------------------------------------------------
__global__ void k_final(const float* __restrict__ gsum,
                        const float* __restrict__ gcnt,
                        const float* __restrict__ bo,
                        float* __restrict__ out)
{
    const int g = threadIdx.x;
    if (g < N_GRAPHS)
        out[g] = gsum[g] / fmaxf(gcnt[g], 1.f) + bo[0];
}

// ---------------------------------------------------------------------------
extern "C" void kernel_launch(void* const* d_in, const int* in_sizes, int n_in,
                              void* d_out, int out_size, void* d_ws, size_t ws_size,
                              hipStream_t stream)
{
    const float* x      = (const float*)d_in[0];
    const float* ea     = (const float*)d_in[1];
    const int*   ei     = (const int*)  d_in[2];
    const int*   batch  = (const int*)  d_in[3];
    const float* Wn     = (const float*)d_in[4];
    const float* bn     = (const float*)d_in[5];
    const float* We     = (const float*)d_in[6];
    const float* be     = (const float*)d_in[7];
    const float* Wm     = (const float*)d_in[8];
    const float* bm     = (const float*)d_in[9];
    const float* Wu     = (const float*)d_in[10];
    const float* bu     = (const float*)d_in[11];
    const float* Wo     = (const float*)d_in[12];
    const float* bo     = (const float*)d_in[13];

    float*  ws   = (float*)d_ws;
    float2* vals = (float2*)(ws + VALS_OFF);
    float*  abc  = ws + ABC_OFF;
    float*  gsum = ws + GSUM_OFF;
    float*  gcnt = ws + GCNT_OFF;
    int*    bcur = (int*)(ws + BCUR_OFF);
    float*  out  = (float*)d_out;

    k_prep<<<1, 256, 0, stream>>>(bcur, abc, gsum, gcnt, Wn, bn, We, be, Wm, bm);
    k_bin<<<NCHUNK, 256, 0, stream>>>(x, ea, ei, bcur, vals);
    k_fused<<<NB, 256, 0, stream>>>(vals, bcur, abc, Wu, bu, Wo, batch, gsum, gcnt);
    k_final<<<1, 64, 0, stream>>>(gsum, gcnt, bo, out);
}

// Round 10
// 58.527 us; speedup vs baseline: 7.2866x; 1.0960x over previous
//
#include <hip/hip_runtime.h>

#define N_NODES 50000
#define N_EDGES 800000
#define N_GRAPHS 64
#define H 64
#define BN 64                                    // nodes per bucket
#define NB ((N_NODES + BN - 1) / BN)             // 782
#define CAP 1280                                 // max records/bucket
#define CHUNK 2048
#define EPT (CHUNK / 256)                        // 8 edges per thread
#define NCHUNK ((N_EDGES + CHUNK - 1) / CHUNK)   // 391
#define RPT ((CAP + 255) / 256)                  // 5 records per thread (k_fused)

// ws layout (float units)
#define VALS_OFF  0                              // float2[NB*CAP] = 8.0 MB
#define ABC_OFF   (NB * CAP * 2)
#define GSUM_OFF  (ABC_OFF + 3 * H)
#define GCNT_OFF  (GSUM_OFF + N_GRAPHS)
#define BCUR_OFF  (GCNT_OFF + N_GRAPHS)          // int[NB]

// ---------------------------------------------------------------------------
__global__ __launch_bounds__(256) void k_prep(
    int* __restrict__ bcur, float* __restrict__ abc,
    float* __restrict__ gsum, float* __restrict__ gcnt,
    const float* __restrict__ Wn, const float* __restrict__ bn,
    const float* __restrict__ We, const float* __restrict__ be,
    const float* __restrict__ Wm, const float* __restrict__ bm)
{
    const int t = threadIdx.x;
    for (int i = t; i < NB; i += 256) bcur[i] = 0;
    if (t < N_GRAPHS) { gsum[t] = 0.f; gcnt[t] = 0.f; }
    if (t < H) {
        const int k = t;
        float a = 0.f, b = 0.f, c = 0.f;
        #pragma unroll
        for (int i = 0; i < H; ++i) {
            float wt = Wm[i * H + k];
            float wb = Wm[(H + i) * H + k];
            a = fmaf(Wn[i], wt, a);
            b = fmaf(We[i], wb, b);
            c = fmaf(bn[i], wt, c);
            c = fmaf(be[i], wb, c);
        }
        abc[k]         = a;
        abc[H + k]     = b;
        abc[2 * H + k] = c + bm[k];
    }
}

// ---------------------------------------------------------------------------
// k_bin: register-staged scatter. All loads for a thread's 8 edges are
// issued up front (one latency exposure); hist/ticket/scatter run from regs.
// Local dst (6 bits) packed into ea's low mantissa bits (rel err ~7.5e-6).
__global__ __launch_bounds__(256) void k_bin(
    const float* __restrict__ x, const float* __restrict__ ea,
    const int* __restrict__ ei, int* __restrict__ bcur,
    float2* __restrict__ vals)
{
    __shared__ int lh[NB], lbase[NB], lcur[NB];
    const int t = threadIdx.x;
    for (int b = t; b < NB; b += 256) { lh[b] = 0; lcur[b] = 0; }

    const int e0 = blockIdx.x * CHUNK;
    const int* __restrict__ src = ei;
    const int* __restrict__ dst = ei + N_EDGES;

    int   d[EPT];
    float xv[EPT], ev[EPT];
    bool  ok[EPT];
    #pragma unroll
    for (int k = 0; k < EPT; ++k) {
        const int e = e0 + t + k * 256;
        ok[k] = (e < N_EDGES);
        const int ee = ok[k] ? e : (N_EDGES - 1);
        const int s  = src[ee];
        d[k]  = dst[ee];
        ev[k] = ea[ee];
        xv[k] = x[s];
    }
    __syncthreads();

    #pragma unroll
    for (int k = 0; k < EPT; ++k)
        if (ok[k]) atomicAdd(&lh[d[k] >> 6], 1);
    __syncthreads();

    for (int b = t; b < NB; b += 256) {
        const int v = lh[b];
        if (v) lbase[b] = atomicAdd(&bcur[b], v);
    }
    __syncthreads();

    #pragma unroll
    for (int k = 0; k < EPT; ++k) {
        if (ok[k]) {
            const int b  = d[k] >> 6;
            const int lp = atomicAdd(&lcur[b], 1);
            const unsigned uy = (__float_as_uint(ev[k]) & 0xFFFFFFC0u) |
                                (unsigned)(d[k] & (BN - 1));
            vals[b * CAP + lbase[b] + lp] = make_float2(xv[k], __uint_as_float(uy));
        }
    }
}

// ---------------------------------------------------------------------------
// k_fused: per bucket — records into REGISTERS + LDS histogram, wave-0
// shuffle scan, regs -> node-sorted LDS, then per-wave: aggregate 16 nodes
// (uniform LDS reads), matvec (Wu column in VGPRs, row broadcast via LDS),
// ReLU-dot, shfl-reduce, pool into LDS graph bins -> global atomics.
__global__ __launch_bounds__(256) void k_fused(
    const float2* __restrict__ vals, const int* __restrict__ bcur,
    const float* __restrict__ abc, const float* __restrict__ Wu,
    const float* __restrict__ bu, const float* __restrict__ Wo,
    const int* __restrict__ batch,
    float* __restrict__ gsum, float* __restrict__ gcnt)
{
    __shared__ float2 stB[CAP];                 // node-sorted records (10.24 KB)
    __shared__ int lh[BN], le[BN], lc[BN];
    __shared__ __align__(16) float sA[4][72];   // per-wave aggregate row
    __shared__ float lsum[N_GRAPHS], lcnt[N_GRAPHS];

    const int t    = threadIdx.x;
    const int lane = t & 63;
    const int w    = t >> 6;
    const int b    = blockIdx.x;
    const int base = b * CAP;

    const float A   = abc[lane];
    const float B   = abc[H + lane];
    const float C   = abc[2 * H + lane];
    const float bul = bu[lane];
    const float wol = Wo[lane];
    float wr[64];
    #pragma unroll
    for (int i = 0; i < 64; ++i) wr[i] = Wu[i * H + lane];

    if (t < BN) lh[t] = 0;
    if (t < N_GRAPHS) { lsum[t] = 0.f; lcnt[t] = 0.f; }
    __syncthreads();

    int m = bcur[b];
    if (m > CAP) m = CAP;

    // load records to registers + histogram
    float2 r[RPT];
    #pragma unroll
    for (int k = 0; k < RPT; ++k) {
        const int i = t + k * 256;
        if (i < m) {
            r[k] = vals[base + i];
            atomicAdd(&lh[__float_as_uint(r[k].y) & (BN - 1)], 1);
        }
    }
    __syncthreads();

    // exclusive scan of 64 bins (wave 0, shuffle scan)
    if (t < BN) {
        const int v = lh[t];
        int incl = v;
        #pragma unroll
        for (int d = 1; d < BN; d <<= 1) {
            const int up = __shfl_up(incl, d);
            if (lane >= d) incl += up;
        }
        le[t] = incl - v;
        lc[t] = incl - v;
    }
    __syncthreads();

    // regs -> node-sorted LDS
    #pragma unroll
    for (int k = 0; k < RPT; ++k) {
        const int i = t + k * 256;
        if (i < m) {
            const int rk = atomicAdd(&lc[__float_as_uint(r[k].y) & (BN - 1)], 1);
            stB[rk] = r[k];
        }
    }
    __syncthreads();

    // per-wave: 16 nodes each
    #define MSG(q) fmaxf(fmaf((q).x, A, fmaf((q).y, B, C)), 0.f)
    for (int qn = 0; qn < BN / 4; ++qn) {
        const int ln   = w * (BN / 4) + qn;
        const int node = b * BN + ln;
        const int off  = le[ln];
        const int c    = lh[ln];

        float s0 = 0.f, s1 = 0.f, s2 = 0.f, s3 = 0.f;
        int j = 0;
        for (; j + 8 <= c; j += 8) {
            const float2 q0 = stB[off + j + 0], q1 = stB[off + j + 1];
            const float2 q2 = stB[off + j + 2], q3 = stB[off + j + 3];
            const float2 q4 = stB[off + j + 4], q5 = stB[off + j + 5];
            const float2 q6 = stB[off + j + 6], q7 = stB[off + j + 7];
            s0 += MSG(q0); s1 += MSG(q1); s2 += MSG(q2); s3 += MSG(q3);
            s0 += MSG(q4); s1 += MSG(q5); s2 += MSG(q6); s3 += MSG(q7);
        }
        for (; j < c; ++j) { const float2 q = stB[off + j]; s0 += MSG(q); }
        const float s = (s0 + s1) + (s2 + s3);

        sA[w][lane] = s;
        float t0 = 0.f, t1 = 0.f, t2 = 0.f, t3 = 0.f;
        #pragma unroll
        for (int i = 0; i < 64; i += 4) {
            const float4 av = *(const float4*)&sA[w][i];
            t0 = fmaf(av.x, wr[i + 0], t0);
            t1 = fmaf(av.y, wr[i + 1], t1);
            t2 = fmaf(av.z, wr[i + 2], t2);
            t3 = fmaf(av.w, wr[i + 3], t3);
        }
        const float tk = (t0 + t1) + (t2 + t3);
        float u = fmaxf(tk + bul, 0.f) * wol;
        #pragma unroll
        for (int off2 = 32; off2 > 0; off2 >>= 1)
            u += __shfl_xor(u, off2);
        if (lane == 0 && node < N_NODES) {
            const int g = batch[node];
            atomicAdd(&lsum[g], u);
            atomicAdd(&lcnt[g], 1.f);
        }
    }
    #undef MSG
    __syncthreads();
    if (t < N_GRAPHS && lcnt[t] != 0.f) {
        atomicAdd(&gsum[t], lsum[t]);
        atomicAdd(&gcnt[t], lcnt[t]);
    }
}

// ---------------------------------------------------------------------------
__global__ void k_final(const float* __restrict__ gsum,
                        const float* __restrict__ gcnt,
                        const float* __restrict__ bo,
                        float* __restrict__ out)
{
    const int g = threadIdx.x;
    if (g < N_GRAPHS)
        out[g] = gsum[g] / fmaxf(gcnt[g], 1.f) + bo[0];
}

// ---------------------------------------------------------------------------
extern "C" void kernel_launch(void* const* d_in, const int* in_sizes, int n_in,
                              void* d_out, int out_size, void* d_ws, size_t ws_size,
                              hipStream_t stream)
{
    const float* x      = (const float*)d_in[0];
    const float* ea     = (const float*)d_in[1];
    const int*   ei     = (const int*)  d_in[2];
    const int*   batch  = (const int*)  d_in[3];
    const float* Wn     = (const float*)d_in[4];
    const float* bn     = (const float*)d_in[5];
    const float* We     = (const float*)d_in[6];
    const float* be     = (const float*)d_in[7];
    const float* Wm     = (const float*)d_in[8];
    const float* bm     = (const float*)d_in[9];
    const float* Wu     = (const float*)d_in[10];
    const float* bu     = (const float*)d_in[11];
    const float* Wo     = (const float*)d_in[12];
    const float* bo     = (const float*)d_in[13];

    float*  ws   = (float*)d_ws;
    float2* vals = (float2*)(ws + VALS_OFF);
    float*  abc  = ws + ABC_OFF;
    float*  gsum = ws + GSUM_OFF;
    float*  gcnt = ws + GCNT_OFF;
    int*    bcur = (int*)(ws + BCUR_OFF);
    float*  out  = (float*)d_out;

    k_prep<<<1, 256, 0, stream>>>(bcur, abc, gsum, gcnt, Wn, bn, We, be, Wm, bm);
    k_bin<<<NCHUNK, 256, 0, stream>>>(x, ea, ei, bcur, vals);
    k_fused<<<NB, 256, 0, stream>>>(vals, bcur, abc, Wu, bu, Wo, batch, gsum, gcnt);
    k_final<<<1, 64, 0, stream>>>(gsum, gcnt, bo, out);
}